// Round 1
// baseline (823.290 us; speedup 1.0000x reference)
//
#include <hip/hip_runtime.h>
#include <cstdint>
#include <cstddef>

#define Bb  256
#define Ss  196
#define Hh  1024
#define SP1 197
#define Mm  50176   // Bb*Ss

typedef float  f32x4 __attribute__((ext_vector_type(4)));
typedef short  s16x8 __attribute__((ext_vector_type(8)));
typedef unsigned short u16;

__device__ __forceinline__ u16 f2b(float f) {
  uint32_t u = __float_as_uint(f);
  u += 0x7FFFu + ((u >> 16) & 1u);     // RNE to bf16
  return (u16)(u >> 16);
}

// ---------------- K0: transpose + convert W_v [K][N] f32 -> WvT [N][K] bf16 ----
__global__ __launch_bounds__(256) void k_transpose_cvt(const float* __restrict__ Wv,
                                                       u16* __restrict__ WvT) {
  __shared__ float t[64][65];
  int k0 = (blockIdx.x & 15) * 64;
  int n0 = (blockIdx.x >> 4) * 64;
  int tid = threadIdx.x;
#pragma unroll
  for (int i = 0; i < 16; ++i) {
    int idx = i * 256 + tid;
    int r = idx >> 6, c = idx & 63;
    t[r][c] = Wv[(size_t)(k0 + r) * Hh + n0 + c];
  }
  __syncthreads();
#pragma unroll
  for (int i = 0; i < 16; ++i) {
    int idx = i * 256 + tid;
    int r = idx >> 6, c = idx & 63;
    WvT[(size_t)(n0 + r) * Hh + k0 + c] = f2b(t[c][r]);
  }
}

// ---------------- small GEMM: Y[b,j] = act(sum_k X[b,k] W[k,j] + bias[j]) ------
// B=256 batches, K=1024 fixed. grid = (N/256) * 16 batch-tiles of 16.
__global__ __launch_bounds__(256) void k_small_gemm(const float* __restrict__ X, int ldx,
                                                    const float* __restrict__ W, int ldw,
                                                    const float* __restrict__ bias,
                                                    float* __restrict__ Y, int ldy,
                                                    int N, int act) {
  int nct = N >> 8;
  int ct = blockIdx.x % nct, bt = blockIdx.x / nct;
  int tid = threadIdx.x;
  int j = ct * 256 + tid;
  __shared__ float xs[16][64];
  float acc[16];
#pragma unroll
  for (int b = 0; b < 16; ++b) acc[b] = 0.f;
  int bl = tid >> 4, kl4 = (tid & 15) * 4;
  for (int k0 = 0; k0 < 1024; k0 += 64) {
    f32x4 xv = *(const f32x4*)&X[(size_t)(bt * 16 + bl) * ldx + k0 + kl4];
    *(f32x4*)&xs[bl][kl4] = xv;
    __syncthreads();
    for (int kl = 0; kl < 64; kl += 4) {
      float w0 = W[(size_t)(k0 + kl + 0) * ldw + j];
      float w1 = W[(size_t)(k0 + kl + 1) * ldw + j];
      float w2 = W[(size_t)(k0 + kl + 2) * ldw + j];
      float w3 = W[(size_t)(k0 + kl + 3) * ldw + j];
#pragma unroll
      for (int b = 0; b < 16; ++b) {
        f32x4 x = *(const f32x4*)&xs[b][kl];
        acc[b] += x.x * w0; acc[b] += x.y * w1;
        acc[b] += x.z * w2; acc[b] += x.w * w3;
      }
    }
    __syncthreads();
  }
#pragma unroll
  for (int b = 0; b < 16; ++b) {
    float r = acc[b] + bias[j];
    if (act) r = tanhf(r);
    Y[(size_t)(bt * 16 + b) * ldy + j] = r;
  }
}

// ---------------- zS[b] = b_z + sum_j Wz[j]*tanh(sv[b,j] + hh[b,j]) ------------
__global__ __launch_bounds__(256) void k_zs(const float* __restrict__ sv,
                                            const float* __restrict__ hh,
                                            const float* __restrict__ Wz,
                                            const float* __restrict__ bz,
                                            float* __restrict__ zS) {
  int b = blockIdx.x, tid = threadIdx.x;
  float p = 0.f;
  for (int j = tid; j < Hh; j += 256)
    p += Wz[j] * tanhf(sv[(size_t)b * Hh + j] + hh[(size_t)b * Hh + j]);
#pragma unroll
  for (int d = 1; d < 64; d <<= 1) p += __shfl_xor(p, d);
  __shared__ float red[4];
  int wid = tid >> 6, lane = tid & 63;
  if (lane == 0) red[wid] = p;
  __syncthreads();
  if (tid == 0) zS[b] = red[0] + red[1] + red[2] + red[3] + bz[0];
}

// ---------------- K3: fused big GEMM + tanh + Wz-dot epilogue ------------------
// zpart[nt][row] = sum_{j in n-tile} Wz[j]*tanh( (v·Wv)[row,j] + bv[j] + hh[b(row),j] )
#define BM 128
#define BN 128
#define BK 64
__global__ __launch_bounds__(256) void k_big(const float* __restrict__ V,
                                             const u16* __restrict__ WvT,
                                             const float* __restrict__ bv,
                                             const float* __restrict__ hh,
                                             const float* __restrict__ Wz,
                                             float* __restrict__ zpart) {
  __shared__ __align__(16) u16 As[BM * BK];   // [row][k] bf16, 16 KB
  __shared__ __align__(16) u16 Bs[BN * BK];   // [n][k]  bf16, 16 KB
  __shared__ float wz_s[128], bv_s[128], hh_s[2][128], z_s[128];

  int bid = blockIdx.x;
  int xcd = bid & 7, idx = bid >> 3;
  int lin = xcd * 392 + idx;          // 3136/8 = 392 per XCD; same-mt blocks share an XCD
  int mt = lin >> 3, nt = lin & 7;
  int row0 = mt * BM, n0 = nt * BN;

  int tid = threadIdx.x;
  int lane = tid & 63, wid = tid >> 6;
  int wm = wid >> 1, wn = wid & 1;

  int b0 = row0 / Ss;
  int rsplit = (b0 + 1) * Ss - row0;  // rows >= rsplit belong to batch b0+1
  int b1 = (rsplit < BM) ? (b0 + 1) : b0;
  if (tid < 128) {
    wz_s[tid] = Wz[n0 + tid];
    bv_s[tid] = bv[n0 + tid];
    hh_s[0][tid] = hh[(size_t)b0 * Hh + n0 + tid];
    hh_s[1][tid] = hh[(size_t)b1 * Hh + n0 + tid];
  }

  f32x4 acc[4][4];
  f32x4 z4 = {0.f, 0.f, 0.f, 0.f};
#pragma unroll
  for (int m = 0; m < 4; ++m)
#pragma unroll
    for (int n = 0; n < 4; ++n) acc[m][n] = z4;

  int ar = tid >> 4, ac = (tid & 15) * 4;        // A staging: row i*16+ar, col ac
  int brl = lane >> 3, bc = (lane & 7) * 8;      // B staging lane offsets

  for (int kt = 0; kt < 16; ++kt) {
    int k0 = kt * BK;
    f32x4 av[8];
#pragma unroll
    for (int i = 0; i < 8; ++i)
      av[i] = *(const f32x4*)&V[(size_t)(row0 + i * 16 + ar) * Hh + k0 + ac];
    __syncthreads();   // previous tile's compute done before overwrite
#pragma unroll
    for (int i = 0; i < 4; ++i) {
      int rb = (wid * 4 + i) * 8;                // wave-uniform
      const u16* g = &WvT[(size_t)(n0 + rb + brl) * Hh + k0 + bc];
      __builtin_amdgcn_global_load_lds(
          (const __attribute__((address_space(1))) unsigned int*)(const void*)g,
          (__attribute__((address_space(3))) unsigned int*)(void*)&Bs[rb * BK],
          16, 0, 0);
    }
#pragma unroll
    for (int i = 0; i < 8; ++i) {
      ushort4 w;
      w.x = f2b(av[i].x); w.y = f2b(av[i].y);
      w.z = f2b(av[i].z); w.w = f2b(av[i].w);
      *(ushort4*)&As[(i * 16 + ar) * BK + ac] = w;
    }
    __syncthreads();
#pragma unroll
    for (int kk = 0; kk < BK; kk += 32) {
      s16x8 afr[4], bfr[4];
#pragma unroll
      for (int m = 0; m < 4; ++m)
        afr[m] = *(const s16x8*)&As[(wm * 64 + m * 16 + (lane & 15)) * BK + kk + (lane >> 4) * 8];
#pragma unroll
      for (int n = 0; n < 4; ++n)
        bfr[n] = *(const s16x8*)&Bs[(wn * 64 + n * 16 + (lane & 15)) * BK + kk + (lane >> 4) * 8];
#pragma unroll
      for (int m = 0; m < 4; ++m)
#pragma unroll
        for (int n = 0; n < 4; ++n)
          acc[m][n] = __builtin_amdgcn_mfma_f32_16x16x32_bf16(afr[m], bfr[n], acc[m][n], 0, 0, 0);
    }
  }

  // epilogue: z-partial = sum_cols Wz*tanh(acc + bv + hh)
  int cl = lane & 15, rg = lane >> 4;
  float pz[4][4];
#pragma unroll
  for (int m = 0; m < 4; ++m)
#pragma unroll
    for (int j = 0; j < 4; ++j) pz[m][j] = 0.f;
#pragma unroll
  for (int n = 0; n < 4; ++n) {
    int col = wn * 64 + n * 16 + cl;
    float wzv = wz_s[col], bvv = bv_s[col];
    float h0 = hh_s[0][col], h1 = hh_s[1][col];
#pragma unroll
    for (int m = 0; m < 4; ++m)
#pragma unroll
      for (int j = 0; j < 4; ++j) {
        int r = wm * 64 + m * 16 + rg * 4 + j;
        float hv = (r >= rsplit) ? h1 : h0;
        pz[m][j] += wzv * tanhf(acc[m][n][j] + bvv + hv);
      }
  }
#pragma unroll
  for (int m = 0; m < 4; ++m)
#pragma unroll
    for (int j = 0; j < 4; ++j) {
      float vv = pz[m][j];
      vv += __shfl_xor(vv, 1); vv += __shfl_xor(vv, 2);
      vv += __shfl_xor(vv, 4); vv += __shfl_xor(vv, 8);
      pz[m][j] = vv;
    }
  __syncthreads();
  if (wn == 0 && cl == 0) {
#pragma unroll
    for (int m = 0; m < 4; ++m)
#pragma unroll
      for (int j = 0; j < 4; ++j)
        z_s[wm * 64 + m * 16 + rg * 4 + j] = pz[m][j];
  }
  __syncthreads();
  if (wn == 1 && cl == 0) {
#pragma unroll
    for (int m = 0; m < 4; ++m)
#pragma unroll
      for (int j = 0; j < 4; ++j)
        z_s[wm * 64 + m * 16 + rg * 4 + j] += pz[m][j];
  }
  __syncthreads();
  if (tid < 128)
    zpart[(size_t)nt * Mm + row0 + tid] = z_s[tid];
}

// ---------------- K4: softmax over 197 per batch -------------------------------
__global__ __launch_bounds__(256) void k_softmax(const float* __restrict__ zpart,
                                                 const float* __restrict__ zS,
                                                 const float* __restrict__ bz,
                                                 float* __restrict__ outA) {
  int b = blockIdx.x, tid = threadIdx.x;
  float z = -1e30f;
  if (tid < Ss) {
    float s = 0.f;
#pragma unroll
    for (int nt = 0; nt < 8; ++nt) s += zpart[(size_t)nt * Mm + (size_t)b * Ss + tid];
    z = s + bz[0];
  } else if (tid == Ss) {
    z = zS[b];
  }
  int wid = tid >> 6, lane = tid & 63;
  float m = z;
#pragma unroll
  for (int d = 1; d < 64; d <<= 1) m = fmaxf(m, __shfl_xor(m, d));
  __shared__ float redm[4], reds[4];
  if (lane == 0) redm[wid] = m;
  __syncthreads();
  m = fmaxf(fmaxf(redm[0], redm[1]), fmaxf(redm[2], redm[3]));
  float e = (tid <= Ss) ? expf(z - m) : 0.f;
  float s = e;
#pragma unroll
  for (int d = 1; d < 64; d <<= 1) s += __shfl_xor(s, d);
  if (lane == 0) reds[wid] = s;
  __syncthreads();
  s = reds[0] + reds[1] + reds[2] + reds[3];
  if (tid <= Ss) outA[(size_t)b * SP1 + tid] = e / s;
}

// ---------------- K5: c[b,:] = sum_t a[b,t]*v[b,t,:] + a[b,S]*s[b,:] -----------
__global__ __launch_bounds__(256) void k_ctx(const float* __restrict__ V,
                                             const float* __restrict__ hs,
                                             const float* __restrict__ A,
                                             float* __restrict__ outC) {
  int b = blockIdx.x >> 2;
  int col = (blockIdx.x & 3) * 256 + threadIdx.x;
  __shared__ float a_s[SP1];
  if (threadIdx.x < SP1) a_s[threadIdx.x] = A[(size_t)b * SP1 + threadIdx.x];
  __syncthreads();
  float acc = a_s[Ss] * hs[(size_t)b * 2048 + 1024 + col];   // s half of hs
  const float* vb = &V[(size_t)b * Ss * Hh + col];
#pragma unroll 4
  for (int t = 0; t < Ss; ++t) acc += a_s[t] * vb[(size_t)t * Hh];
  outC[(size_t)b * Hh + col] = acc;
}

// -------------------------------------------------------------------------------
extern "C" void kernel_launch(void* const* d_in, const int* in_sizes, int n_in,
                              void* d_out, int out_size, void* d_ws, size_t ws_size,
                              hipStream_t stream) {
  const float* v   = (const float*)d_in[0];
  const float* h   = (const float*)d_in[1];
  const float* Wfc = (const float*)d_in[2];
  const float* bfc = (const float*)d_in[3];
  const float* Wv  = (const float*)d_in[4];
  const float* bv  = (const float*)d_in[5];
  const float* Wh  = (const float*)d_in[6];
  const float* bh  = (const float*)d_in[7];
  const float* Ws  = (const float*)d_in[8];
  const float* bs  = (const float*)d_in[9];
  const float* Wz  = (const float*)d_in[10];
  const float* bz  = (const float*)d_in[11];
  float* out  = (float*)d_out;
  float* outA = out;                         // [256][197]
  float* outC = out + (size_t)Bb * SP1;      // [256][1024]

  float* ws  = (float*)d_ws;
  float* hs  = ws;                  // 256*2048
  float* hh  = hs + 524288;         // 256*1024  (_h)
  float* sv  = hh + 262144;         // 256*1024  (_s pre-activation)
  float* zS  = sv + 262144;         // 256
  float* zp  = zS + 256;            // 8*50176
  u16*  WvT  = (u16*)(zp + 401408); // 1024*1024 bf16

  k_transpose_cvt<<<256, 256, 0, stream>>>(Wv, WvT);
  k_small_gemm<<<8 * 16, 256, 0, stream>>>(h, Hh, Wfc, 2048, bfc, hs, 2048, 2048, 1);
  k_small_gemm<<<4 * 16, 256, 0, stream>>>(hs, 2048, Wh, Hh, bh, hh, Hh, Hh, 0);
  k_small_gemm<<<4 * 16, 256, 0, stream>>>(hs + 1024, 2048, Ws, Hh, bs, sv, Hh, Hh, 0);
  k_zs<<<256, 256, 0, stream>>>(sv, hh, Wz, bz, zS);
  k_big<<<3136, 256, 0, stream>>>(v, WvT, bv, hh, Wz, zp);
  k_softmax<<<256, 256, 0, stream>>>(zp, zS, bz, outA);
  k_ctx<<<1024, 256, 0, stream>>>(v, hs, outA, outC);
}

// Round 3
// 279.499 us; speedup vs baseline: 2.9456x; 2.9456x over previous
//
#include <hip/hip_runtime.h>
#include <hip/hip_bf16.h>
#include <cstdint>
#include <cstddef>

#define Bb  256
#define Ss  196
#define Hh  1024
#define SP1 197
#define Mm  50176   // Bb*Ss

typedef float  f32x4 __attribute__((ext_vector_type(4)));
typedef short  s16x8 __attribute__((ext_vector_type(8)));
typedef unsigned short u16;

__device__ __forceinline__ u16 f2b(float f) {
  __hip_bfloat16 b = __float2bfloat16(f);   // RNE
  u16 r; __builtin_memcpy(&r, &b, 2); return r;
}

// ---------------- K0: transpose + convert W_v [K][N] f32 -> WvT_sw [N][K] bf16
// with baked XOR swizzle: u16 index = n*1024 + (k ^ ((n&7)<<3)).
__global__ __launch_bounds__(256) void k_transpose_cvt(const float* __restrict__ Wv,
                                                       u16* __restrict__ WvT) {
  __shared__ float t[64][65];
  int k0 = (blockIdx.x & 15) * 64;
  int n0 = (blockIdx.x >> 4) * 64;
  int tid = threadIdx.x;
#pragma unroll
  for (int i = 0; i < 16; ++i) {
    int idx = i * 256 + tid;
    int r = idx >> 6, c = idx & 63;
    t[r][c] = Wv[(size_t)(k0 + r) * Hh + n0 + c];
  }
  __syncthreads();
#pragma unroll
  for (int i = 0; i < 16; ++i) {
    int idx = i * 256 + tid;
    int r = idx >> 6, c = idx & 63;          // r: n-dim, c: k-dim (within tile)
    WvT[(size_t)(n0 + r) * Hh + ((k0 + c) ^ ((r & 7) << 3))] = f2b(t[c][r]);
  }
}

// ---------------- small GEMM core: Y[16 rows x 64 cols] = act(X@W + b) --------
// 4 waves, wave w owns K range [w*256, w*256+256); no barriers in K loop.
__device__ __forceinline__ void small_gemm_core(int bid, int nct,
    const float* __restrict__ X, int ldx,
    const float* __restrict__ W, int ldw,
    const float* __restrict__ bias,
    float* __restrict__ Y, int ldy, int act) {
  __shared__ float xs[4][16][64];
  int tid = threadIdx.x, lane = tid & 63, w = tid >> 6;
  int ct = bid % nct, bt = bid / nct;
  int col = ct * 64 + lane;
  float acc[16];
#pragma unroll
  for (int b = 0; b < 16; ++b) acc[b] = 0.f;
  int xr = lane >> 2, xc = (lane & 3) * 16;
  for (int kc = 0; kc < 4; ++kc) {
    int kb = w * 256 + kc * 64;
#pragma unroll
    for (int q = 0; q < 4; ++q)
      *(f32x4*)&xs[w][xr][xc + q * 4] =
          *(const f32x4*)&X[(size_t)(bt * 16 + xr) * ldx + kb + xc + q * 4];
    // wave-private region: compiler's lgkmcnt ordering suffices, no barrier
    for (int kl = 0; kl < 64; kl += 4) {
      float w0 = W[(size_t)(kb + kl + 0) * ldw + col];
      float w1 = W[(size_t)(kb + kl + 1) * ldw + col];
      float w2 = W[(size_t)(kb + kl + 2) * ldw + col];
      float w3 = W[(size_t)(kb + kl + 3) * ldw + col];
#pragma unroll
      for (int b = 0; b < 16; ++b) {
        f32x4 x = *(const f32x4*)&xs[w][b][kl];
        acc[b] += x.x * w0 + x.y * w1 + x.z * w2 + x.w * w3;
      }
    }
  }
  // cross-wave K reduction: reuse xs as red[w][b][col]
#pragma unroll
  for (int b = 0; b < 16; ++b) xs[w][b][lane] = acc[b];
  __syncthreads();
#pragma unroll
  for (int q = 0; q < 4; ++q) {
    int b = w * 4 + q;
    float s = xs[0][b][lane] + xs[1][b][lane] + xs[2][b][lane] + xs[3][b][lane]
            + bias[col];
    if (act) s = tanhf(s);
    Y[(size_t)(bt * 16 + b) * ldy + col] = s;
  }
}

// hs = tanh(h@Wfc + bfc): grid 16*32 = 512 blocks
__global__ __launch_bounds__(256) void k_fc(const float* __restrict__ h,
                                            const float* __restrict__ Wfc,
                                            const float* __restrict__ bfc,
                                            float* __restrict__ hs) {
  small_gemm_core(blockIdx.x, 32, h, Hh, Wfc, 2048, bfc, hs, 2048, 1);
}

// hh = h1@Wh + bh  and  sv = s@Ws + bs in one launch: grid 512 (256 each)
__global__ __launch_bounds__(256) void k_dual(const float* __restrict__ hs,
                                              const float* __restrict__ Wh,
                                              const float* __restrict__ bh,
                                              const float* __restrict__ Ws_,
                                              const float* __restrict__ bs_,
                                              float* __restrict__ hhp,
                                              float* __restrict__ svp) {
  int bid = blockIdx.x;
  int sel = bid >= 256;
  small_gemm_core(bid - (sel << 8), 16,
                  sel ? hs + 1024 : hs, 2048,
                  sel ? Ws_ : Wh, Hh,
                  sel ? bs_ : bh,
                  sel ? svp : hhp, Hh, 0);
}

// ---------------- K3: fused big GEMM + tanh + Wz-dot epilogue ------------------
#define BM 64
#define BN 256
#define BK 64
#define LDA 72   // padded u16 stride for As (144 B)
__global__ __launch_bounds__(256, 3) void k_big(const float* __restrict__ V,
                                                const u16* __restrict__ WvT,
                                                const float* __restrict__ bv,
                                                const float* __restrict__ hh,
                                                const float* __restrict__ Wz,
                                                float* __restrict__ zpart) {
  __shared__ __align__(16) u16 As[BM * LDA];      // 9216 B
  __shared__ __align__(16) u16 Bs[BN * BK];       // 32768 B
  __shared__ float wz_s[BN], bv_s[BN], hh_s[2][BN];
  __shared__ float zred[4][BM];

  int bid = blockIdx.x;
  int lin = (bid & 7) * 392 + (bid >> 3);   // 3136/8: same-mt group on one XCD
  int mt = lin >> 2, nt = lin & 3;
  int row0 = mt * BM, n0 = nt * BN;

  int tid = threadIdx.x;
  int lane = tid & 63, wid = tid >> 6;      // 4 waves; wn = wid

  int b0 = row0 / Ss;
  int rsplit = (b0 + 1) * Ss - row0;        // rows >= rsplit -> batch b0+1
  int b1 = (rsplit < BM) ? b0 + 1 : b0;
  wz_s[tid] = Wz[n0 + tid];
  bv_s[tid] = bv[n0 + tid];
  hh_s[0][tid] = hh[(size_t)b0 * Hh + n0 + tid];
  hh_s[1][tid] = hh[(size_t)b1 * Hh + n0 + tid];

  f32x4 acc[4][4];
  f32x4 zz = {0.f, 0.f, 0.f, 0.f};
#pragma unroll
  for (int m = 0; m < 4; ++m)
#pragma unroll
    for (int n = 0; n < 4; ++n) acc[m][n] = zz;

  int arow = tid >> 4;                 // 0..15 (+ j*16)
  int acol = (tid & 15) * 4;
  const float* Ap = V + (size_t)(row0 + arow) * Hh + acol;

  int bsub = lane >> 3;                // 0..7
  int bko  = (lane & 7) * 8;           // u16 k offset in window (linear source:
                                       // storage is pre-swizzled, so linear reads
                                       // produce swizzled LDS — rule 21)

  f32x4 av[4];
#pragma unroll
  for (int j = 0; j < 4; ++j) av[j] = *(const f32x4*)(Ap + (size_t)j * 16 * Hh);

  for (int kt = 0; kt < 16; ++kt) {
    int k0 = kt * BK;
    __syncthreads();                   // prev compute done; LDS writable
#pragma unroll
    for (int i = 0; i < 8; ++i) {
      int r = wid * 64 + i * 8;
      const u16* g = WvT + (size_t)(n0 + r + bsub) * Hh + (k0 + bko);
      __builtin_amdgcn_global_load_lds(
          (const __attribute__((address_space(1))) unsigned int*)(const void*)g,
          (__attribute__((address_space(3))) unsigned int*)(void*)&Bs[r * BK],
          16, 0, 0);
    }
#pragma unroll
    for (int j = 0; j < 4; ++j) {
      ushort4 w;
      w.x = f2b(av[j].x); w.y = f2b(av[j].y);
      w.z = f2b(av[j].z); w.w = f2b(av[j].w);
      *(ushort4*)&As[(arow + j * 16) * LDA + acol] = w;
    }
    if (kt < 15) {
#pragma unroll
      for (int j = 0; j < 4; ++j)
        av[j] = *(const f32x4*)(Ap + (size_t)j * 16 * Hh + k0 + BK);
    }
    __syncthreads();                   // drains vmcnt(B) + lgkm(A)
#pragma unroll
    for (int ks = 0; ks < 2; ++ks) {
      int kk = ks * 32 + (lane >> 4) * 8;
      s16x8 afr[4], bfr[4];
#pragma unroll
      for (int m = 0; m < 4; ++m)
        afr[m] = *(const s16x8*)&As[(m * 16 + (lane & 15)) * LDA + kk];
#pragma unroll
      for (int n = 0; n < 4; ++n) {
        int r = wid * 64 + n * 16 + (lane & 15);
        bfr[n] = *(const s16x8*)&Bs[r * BK + (kk ^ ((r & 7) << 3))];
      }
#pragma unroll
      for (int m = 0; m < 4; ++m)
#pragma unroll
        for (int n = 0; n < 4; ++n)
          acc[m][n] = __builtin_amdgcn_mfma_f32_16x16x32_bf16(afr[m], bfr[n], acc[m][n], 0, 0, 0);
    }
  }

  // epilogue: z-partial = sum over this block's 256 cols of Wz*tanh(acc+bv+hh)
  int cl = lane & 15, rg = lane >> 4;
  float pz[4][4];
#pragma unroll
  for (int m = 0; m < 4; ++m)
#pragma unroll
    for (int j = 0; j < 4; ++j) pz[m][j] = 0.f;
#pragma unroll
  for (int n = 0; n < 4; ++n) {
    int col = wid * 64 + n * 16 + cl;
    float wzv = wz_s[col], bvv = bv_s[col];
    float h0 = hh_s[0][col], h1 = hh_s[1][col];
#pragma unroll
    for (int m = 0; m < 4; ++m)
#pragma unroll
      for (int j = 0; j < 4; ++j) {
        int r = m * 16 + rg * 4 + j;
        float hv = (r >= rsplit) ? h1 : h0;
        pz[m][j] += wzv * tanhf(acc[m][n][j] + bvv + hv);
      }
  }
#pragma unroll
  for (int m = 0; m < 4; ++m)
#pragma unroll
    for (int j = 0; j < 4; ++j) {
      float vv = pz[m][j];
      vv += __shfl_xor(vv, 1); vv += __shfl_xor(vv, 2);
      vv += __shfl_xor(vv, 4); vv += __shfl_xor(vv, 8);
      pz[m][j] = vv;
    }
  if (cl == 0) {
#pragma unroll
    for (int m = 0; m < 4; ++m)
#pragma unroll
      for (int j = 0; j < 4; ++j)
        zred[wid][m * 16 + rg * 4 + j] = pz[m][j];
  }
  __syncthreads();
  if (tid < BM)
    zpart[(size_t)nt * Mm + row0 + tid] =
        zred[0][tid] + zred[1][tid] + zred[2][tid] + zred[3][tid];
}

// ---------------- K4: softmax over 197 per batch (zS folded in) ----------------
__global__ __launch_bounds__(256) void k_softmax(const float* __restrict__ zpart,
                                                 const float* __restrict__ sv,
                                                 const float* __restrict__ hhp,
                                                 const float* __restrict__ Wz,
                                                 const float* __restrict__ bz,
                                                 float* __restrict__ outA) {
  int b = blockIdx.x, tid = threadIdx.x;
  int wid = tid >> 6, lane = tid & 63;
  __shared__ float redm[4], reds[4];
  __shared__ float zSsh;
  // zS[b] = bz + sum_j Wz[j]*tanh(sv+hh)
  {
    int j0 = tid * 4;
    f32x4 s4 = *(const f32x4*)&sv[(size_t)b * Hh + j0];
    f32x4 h4 = *(const f32x4*)&hhp[(size_t)b * Hh + j0];
    f32x4 w4 = *(const f32x4*)&Wz[j0];
    float p = w4.x * tanhf(s4.x + h4.x) + w4.y * tanhf(s4.y + h4.y)
            + w4.z * tanhf(s4.z + h4.z) + w4.w * tanhf(s4.w + h4.w);
#pragma unroll
    for (int d = 1; d < 64; d <<= 1) p += __shfl_xor(p, d);
    if (lane == 0) redm[wid] = p;
    __syncthreads();
    if (tid == 0) zSsh = redm[0] + redm[1] + redm[2] + redm[3] + bz[0];
    __syncthreads();
  }
  float z = -1e30f;
  if (tid < Ss) {
    float s = 0.f;
#pragma unroll
    for (int nt = 0; nt < 4; ++nt) s += zpart[(size_t)nt * Mm + (size_t)b * Ss + tid];
    z = s + bz[0];
  } else if (tid == Ss) {
    z = zSsh;
  }
  float m = z;
#pragma unroll
  for (int d = 1; d < 64; d <<= 1) m = fmaxf(m, __shfl_xor(m, d));
  if (lane == 0) redm[wid] = m;
  __syncthreads();
  m = fmaxf(fmaxf(redm[0], redm[1]), fmaxf(redm[2], redm[3]));
  float e = (tid <= Ss) ? expf(z - m) : 0.f;
  float s = e;
#pragma unroll
  for (int d = 1; d < 64; d <<= 1) s += __shfl_xor(s, d);
  if (lane == 0) reds[wid] = s;
  __syncthreads();
  s = reds[0] + reds[1] + reds[2] + reds[3];
  if (tid <= Ss) outA[(size_t)b * SP1 + tid] = e / s;
}

// ---------------- K5: c[b,:] = sum_t a[b,t]*v[b,t,:] + a[b,S]*s[b,:] -----------
__global__ __launch_bounds__(256) void k_ctx(const float* __restrict__ V,
                                             const float* __restrict__ hs,
                                             const float* __restrict__ A,
                                             float* __restrict__ outC) {
  int b = blockIdx.x >> 2;
  int col = (blockIdx.x & 3) * 256 + threadIdx.x;
  __shared__ float a_s[SP1];
  if (threadIdx.x < SP1) a_s[threadIdx.x] = A[(size_t)b * SP1 + threadIdx.x];
  __syncthreads();
  float acc = a_s[Ss] * hs[(size_t)b * 2048 + 1024 + col];   // s half of hs
  const float* vb = &V[(size_t)b * Ss * Hh + col];
#pragma unroll 4
  for (int t = 0; t < Ss; ++t) acc += a_s[t] * vb[(size_t)t * Hh];
  outC[(size_t)b * Hh + col] = acc;
}

// -------------------------------------------------------------------------------
extern "C" void kernel_launch(void* const* d_in, const int* in_sizes, int n_in,
                              void* d_out, int out_size, void* d_ws, size_t ws_size,
                              hipStream_t stream) {
  const float* v   = (const float*)d_in[0];
  const float* h   = (const float*)d_in[1];
  const float* Wfc = (const float*)d_in[2];
  const float* bfc = (const float*)d_in[3];
  const float* Wv  = (const float*)d_in[4];
  const float* bv  = (const float*)d_in[5];
  const float* Wh  = (const float*)d_in[6];
  const float* bh  = (const float*)d_in[7];
  const float* Ws  = (const float*)d_in[8];
  const float* bs  = (const float*)d_in[9];
  const float* Wz  = (const float*)d_in[10];
  const float* bz  = (const float*)d_in[11];
  float* out  = (float*)d_out;
  float* outA = out;                         // [256][197]
  float* outC = out + (size_t)Bb * SP1;      // [256][1024]

  float* ws  = (float*)d_ws;
  float* hs  = ws;                  // 256*2048
  float* hh  = hs + 524288;         // 256*1024
  float* sv  = hh + 262144;         // 256*1024
  float* zp  = sv + 262144;         // 4*50176
  u16*  WvT  = (u16*)(zp + 200704); // 1024*1024 bf16 (swizzled)

  k_transpose_cvt<<<256, 256, 0, stream>>>(Wv, WvT);
  k_fc<<<512, 256, 0, stream>>>(h, Wfc, bfc, hs);
  k_dual<<<512, 256, 0, stream>>>(hs, Wh, bh, Ws, bs, hh, sv);
  k_big<<<3136, 256, 0, stream>>>(v, WvT, bv, hh, Wz, zp);
  k_softmax<<<256, 256, 0, stream>>>(zp, sv, hh, Wz, bz, outA);
  k_ctx<<<1024, 256, 0, stream>>>(v, hs, outA, outC);
}

// Round 4
// 262.392 us; speedup vs baseline: 3.1376x; 1.0652x over previous
//
#include <hip/hip_runtime.h>
#include <hip/hip_bf16.h>
#include <cstdint>
#include <cstddef>

#define Bb  256
#define Ss  196
#define Hh  1024
#define SP1 197
#define Mm  50176   // Bb*Ss

typedef float  f32x4 __attribute__((ext_vector_type(4)));
typedef short  s16x8 __attribute__((ext_vector_type(8)));
typedef unsigned short u16;
typedef unsigned short u16x8 __attribute__((ext_vector_type(8)));

__device__ __forceinline__ u16 f2b(float f) {
  __hip_bfloat16 b = __float2bfloat16(f);   // RNE
  u16 r; __builtin_memcpy(&r, &b, 2); return r;
}

// fast tanh: copysign((1-t)/(1+t), x), t=e^{-2|x|}; rel err ~1e-6 (vs bf16 4e-3 budget)
__device__ __forceinline__ float ftanh(float x) {
  float ax = fabsf(x);
  float t = __expf(-2.f * ax);
  float r = (1.f - t) * __builtin_amdgcn_rcpf(1.f + t);
  return copysignf(r, x);
}

// ---------------- K0: transpose + convert W_v [K][N] f32 -> WvT_sw [N][K] bf16
// with baked XOR swizzle: u16 index = n*1024 + (k ^ ((n&7)<<3)).
__global__ __launch_bounds__(256) void k_transpose_cvt(const float* __restrict__ Wv,
                                                       u16* __restrict__ WvT) {
  __shared__ float t[64][65];
  int k0 = (blockIdx.x & 15) * 64;
  int n0 = (blockIdx.x >> 4) * 64;
  int tid = threadIdx.x;
#pragma unroll
  for (int i = 0; i < 16; ++i) {
    int idx = i * 256 + tid;
    int r = idx >> 6, c = idx & 63;
    t[r][c] = Wv[(size_t)(k0 + r) * Hh + n0 + c];
  }
  __syncthreads();
#pragma unroll
  for (int i = 0; i < 16; ++i) {
    int idx = i * 256 + tid;
    int r = idx >> 6, c = idx & 63;          // r: n-dim, c: k-dim (within tile)
    WvT[(size_t)(n0 + r) * Hh + ((k0 + c) ^ ((r & 7) << 3))] = f2b(t[c][r]);
  }
}

// ---------------- small GEMM core: Y[16 rows x 64 cols] = act(X@W + b) --------
__device__ __forceinline__ void small_gemm_core(int bid, int nct,
    const float* __restrict__ X, int ldx,
    const float* __restrict__ W, int ldw,
    const float* __restrict__ bias,
    float* __restrict__ Y, int ldy, int act) {
  __shared__ float xs[4][16][64];
  int tid = threadIdx.x, lane = tid & 63, w = tid >> 6;
  int ct = bid % nct, bt = bid / nct;
  int col = ct * 64 + lane;
  float acc[16];
#pragma unroll
  for (int b = 0; b < 16; ++b) acc[b] = 0.f;
  int xr = lane >> 2, xc = (lane & 3) * 16;
  for (int kc = 0; kc < 4; ++kc) {
    int kb = w * 256 + kc * 64;
#pragma unroll
    for (int q = 0; q < 4; ++q)
      *(f32x4*)&xs[w][xr][xc + q * 4] =
          *(const f32x4*)&X[(size_t)(bt * 16 + xr) * ldx + kb + xc + q * 4];
    for (int kl = 0; kl < 64; kl += 4) {
      float w0 = W[(size_t)(kb + kl + 0) * ldw + col];
      float w1 = W[(size_t)(kb + kl + 1) * ldw + col];
      float w2 = W[(size_t)(kb + kl + 2) * ldw + col];
      float w3 = W[(size_t)(kb + kl + 3) * ldw + col];
#pragma unroll
      for (int b = 0; b < 16; ++b) {
        f32x4 x = *(const f32x4*)&xs[w][b][kl];
        acc[b] += x.x * w0 + x.y * w1 + x.z * w2 + x.w * w3;
      }
    }
  }
#pragma unroll
  for (int b = 0; b < 16; ++b) xs[w][b][lane] = acc[b];
  __syncthreads();
#pragma unroll
  for (int q = 0; q < 4; ++q) {
    int b = w * 4 + q;
    float s = xs[0][b][lane] + xs[1][b][lane] + xs[2][b][lane] + xs[3][b][lane]
            + bias[col];
    if (act) s = ftanh(s);
    Y[(size_t)(bt * 16 + b) * ldy + col] = s;
  }
}

__global__ __launch_bounds__(256) void k_fc(const float* __restrict__ h,
                                            const float* __restrict__ Wfc,
                                            const float* __restrict__ bfc,
                                            float* __restrict__ hs) {
  small_gemm_core(blockIdx.x, 32, h, Hh, Wfc, 2048, bfc, hs, 2048, 1);
}

__global__ __launch_bounds__(256) void k_dual(const float* __restrict__ hs,
                                              const float* __restrict__ Wh,
                                              const float* __restrict__ bh,
                                              const float* __restrict__ Ws_,
                                              const float* __restrict__ bs_,
                                              float* __restrict__ hhp,
                                              float* __restrict__ svp) {
  int bid = blockIdx.x;
  int sel = bid >= 256;
  small_gemm_core(bid - (sel << 8), 16,
                  sel ? hs + 1024 : hs, 2048,
                  sel ? Ws_ : Wh, Hh,
                  sel ? bs_ : bh,
                  sel ? svp : hhp, Hh, 0);
}

// ---------------- K3: fused big GEMM + tanh + Wz-dot epilogue ------------------
// BM=128, 4 waves split N only: wave owns 128x64 (8x4 frags) -> 0.375 LDS
// reads/MFMA (was 0.5). 2 blocks/CU (VGPR ~220).
#define BM 128
#define BN 256
#define BK 64
#define LDA 72   // padded u16 stride for As (144 B, 16B-aligned rows)
__global__ __launch_bounds__(256, 2) void k_big(const float* __restrict__ V,
                                                const u16* __restrict__ WvT,
                                                const float* __restrict__ bv,
                                                const float* __restrict__ hh,
                                                const float* __restrict__ Wz,
                                                float* __restrict__ zpart) {
  __shared__ __align__(16) u16 As[BM * LDA];      // 18432 B
  __shared__ __align__(16) u16 Bs[BN * BK];       // 32768 B
  __shared__ float wz_s[BN], bv_s[BN], hh_s[2][BN];
  __shared__ float zred[4][BM];

  int bid = blockIdx.x;
  int lin = (bid & 7) * 196 + (bid >> 3);   // 1568 = 8*196: bijective XCD swizzle
  int mt = lin >> 2, nt = lin & 3;          // 4 nt of one mt share an XCD (A L2 reuse)
  int row0 = mt * BM, n0 = nt * BN;

  int tid = threadIdx.x;
  int lane = tid & 63, wid = tid >> 6;      // 4 waves; wave = all rows x 64 cols

  int b0 = row0 / Ss;
  int rsplit = (b0 + 1) * Ss - row0;        // rows >= rsplit -> batch b0+1 (BM<Ss: <=1 boundary)
  int b1 = (rsplit < BM) ? b0 + 1 : b0;
  wz_s[tid] = Wz[n0 + tid];
  bv_s[tid] = bv[n0 + tid];
  hh_s[0][tid] = hh[(size_t)b0 * Hh + n0 + tid];
  hh_s[1][tid] = hh[(size_t)b1 * Hh + n0 + tid];

  f32x4 acc[8][4];
  f32x4 zz = {0.f, 0.f, 0.f, 0.f};
#pragma unroll
  for (int m = 0; m < 8; ++m)
#pragma unroll
    for (int n = 0; n < 4; ++n) acc[m][n] = zz;

  int arow = tid >> 3;                 // 0..31 (+ j*32)
  int acol = (tid & 7) * 8;            // 8 floats per thread per row-pass
  const float* Ap = V + (size_t)(row0 + arow) * Hh + acol;

  int bsub = lane >> 3;                // 0..7
  int bko  = (lane & 7) * 8;           // linear source: storage pre-swizzled (rule 21)
  int bxor = (lane & 7) << 3;          // read-side XOR (r&7 == lane&7 for frag reads)

  f32x4 av[8];
#pragma unroll
  for (int j = 0; j < 4; ++j) {
    av[2 * j]     = *(const f32x4*)(Ap + (size_t)j * 32 * Hh);
    av[2 * j + 1] = *(const f32x4*)(Ap + (size_t)j * 32 * Hh + 4);
  }

  for (int kt = 0; kt < 16; ++kt) {
    int k0 = kt * BK;
    __syncthreads();                   // prev compute done; LDS writable
#pragma unroll
    for (int i = 0; i < 8; ++i) {
      int r = wid * 64 + i * 8;
      const u16* g = WvT + (size_t)(n0 + r + bsub) * Hh + (k0 + bko);
      __builtin_amdgcn_global_load_lds(
          (const __attribute__((address_space(1))) unsigned int*)(const void*)g,
          (__attribute__((address_space(3))) unsigned int*)(void*)&Bs[r * BK],
          16, 0, 0);
    }
#pragma unroll
    for (int j = 0; j < 4; ++j) {
      u16x8 w;
      w[0] = f2b(av[2 * j].x);     w[1] = f2b(av[2 * j].y);
      w[2] = f2b(av[2 * j].z);     w[3] = f2b(av[2 * j].w);
      w[4] = f2b(av[2 * j + 1].x); w[5] = f2b(av[2 * j + 1].y);
      w[6] = f2b(av[2 * j + 1].z); w[7] = f2b(av[2 * j + 1].w);
      *(u16x8*)&As[(j * 32 + arow) * LDA + acol] = w;
    }
    if (kt < 15) {
#pragma unroll
      for (int j = 0; j < 4; ++j) {
        av[2 * j]     = *(const f32x4*)(Ap + (size_t)j * 32 * Hh + k0 + BK);
        av[2 * j + 1] = *(const f32x4*)(Ap + (size_t)j * 32 * Hh + k0 + BK + 4);
      }
    }
    __syncthreads();                   // drains vmcnt(B) + lgkm(A)
#pragma unroll
    for (int ks = 0; ks < 2; ++ks) {
      int kk = ks * 32 + (lane >> 4) * 8;
      s16x8 afr[8], bfr[4];
#pragma unroll
      for (int m = 0; m < 8; ++m)
        afr[m] = *(const s16x8*)&As[(m * 16 + (lane & 15)) * LDA + kk];
#pragma unroll
      for (int n = 0; n < 4; ++n) {
        int r = wid * 64 + n * 16 + (lane & 15);
        bfr[n] = *(const s16x8*)&Bs[r * BK + (kk ^ bxor)];
      }
#pragma unroll
      for (int m = 0; m < 8; ++m)
#pragma unroll
        for (int n = 0; n < 4; ++n)
          acc[m][n] = __builtin_amdgcn_mfma_f32_16x16x32_bf16(afr[m], bfr[n], acc[m][n], 0, 0, 0);
    }
  }

  // epilogue: z-partial = sum over this block's 256 cols of Wz*tanh(acc+bv+hh)
  int cl = lane & 15, rg = lane >> 4;
  float pz[8][4];
#pragma unroll
  for (int m = 0; m < 8; ++m)
#pragma unroll
    for (int j = 0; j < 4; ++j) pz[m][j] = 0.f;
#pragma unroll
  for (int n = 0; n < 4; ++n) {
    int col = wid * 64 + n * 16 + cl;
    float wzv = wz_s[col], bvv = bv_s[col];
    float h0 = hh_s[0][col], h1 = hh_s[1][col];
#pragma unroll
    for (int m = 0; m < 8; ++m)
#pragma unroll
      for (int j = 0; j < 4; ++j) {
        int r = m * 16 + rg * 4 + j;
        float hv = (r >= rsplit) ? h1 : h0;
        pz[m][j] += wzv * ftanh(acc[m][n][j] + bvv + hv);
      }
  }
#pragma unroll
  for (int m = 0; m < 8; ++m)
#pragma unroll
    for (int j = 0; j < 4; ++j) {
      float vv = pz[m][j];
      vv += __shfl_xor(vv, 1); vv += __shfl_xor(vv, 2);
      vv += __shfl_xor(vv, 4); vv += __shfl_xor(vv, 8);
      pz[m][j] = vv;
    }
  if (cl == 0) {
#pragma unroll
    for (int m = 0; m < 8; ++m)
#pragma unroll
      for (int j = 0; j < 4; ++j)
        zred[wid][m * 16 + rg * 4 + j] = pz[m][j];
  }
  __syncthreads();
  if (tid < BM)
    zpart[(size_t)nt * Mm + row0 + tid] =
        zred[0][tid] + zred[1][tid] + zred[2][tid] + zred[3][tid];
}

// ---------------- K4: softmax over 197 per batch (zS folded in) ----------------
__global__ __launch_bounds__(256) void k_softmax(const float* __restrict__ zpart,
                                                 const float* __restrict__ sv,
                                                 const float* __restrict__ hhp,
                                                 const float* __restrict__ Wz,
                                                 const float* __restrict__ bz,
                                                 float* __restrict__ outA) {
  int b = blockIdx.x, tid = threadIdx.x;
  int wid = tid >> 6, lane = tid & 63;
  __shared__ float redm[4], reds[4];
  __shared__ float zSsh;
  {
    int j0 = tid * 4;
    f32x4 s4 = *(const f32x4*)&sv[(size_t)b * Hh + j0];
    f32x4 h4 = *(const f32x4*)&hhp[(size_t)b * Hh + j0];
    f32x4 w4 = *(const f32x4*)&Wz[j0];
    float p = w4.x * ftanh(s4.x + h4.x) + w4.y * ftanh(s4.y + h4.y)
            + w4.z * ftanh(s4.z + h4.z) + w4.w * ftanh(s4.w + h4.w);
#pragma unroll
    for (int d = 1; d < 64; d <<= 1) p += __shfl_xor(p, d);
    if (lane == 0) redm[wid] = p;
    __syncthreads();
    if (tid == 0) zSsh = redm[0] + redm[1] + redm[2] + redm[3] + bz[0];
    __syncthreads();
  }
  float z = -1e30f;
  if (tid < Ss) {
    float s = 0.f;
#pragma unroll
    for (int nt = 0; nt < 4; ++nt) s += zpart[(size_t)nt * Mm + (size_t)b * Ss + tid];
    z = s + bz[0];
  } else if (tid == Ss) {
    z = zSsh;
  }
  float m = z;
#pragma unroll
  for (int d = 1; d < 64; d <<= 1) m = fmaxf(m, __shfl_xor(m, d));
  if (lane == 0) redm[wid] = m;
  __syncthreads();
  m = fmaxf(fmaxf(redm[0], redm[1]), fmaxf(redm[2], redm[3]));
  float e = (tid <= Ss) ? expf(z - m) : 0.f;
  float s = e;
#pragma unroll
  for (int d = 1; d < 64; d <<= 1) s += __shfl_xor(s, d);
  if (lane == 0) reds[wid] = s;
  __syncthreads();
  s = reds[0] + reds[1] + reds[2] + reds[3];
  if (tid <= Ss) outA[(size_t)b * SP1 + tid] = e / s;
}

// ---------------- K5: c[b,:] = sum_t a[b,t]*v[b,t,:] + a[b,S]*s[b,:] -----------
__global__ __launch_bounds__(256) void k_ctx(const float* __restrict__ V,
                                             const float* __restrict__ hs,
                                             const float* __restrict__ A,
                                             float* __restrict__ outC) {
  int b = blockIdx.x >> 2;
  int col = (blockIdx.x & 3) * 256 + threadIdx.x;
  __shared__ float a_s[SP1];
  if (threadIdx.x < SP1) a_s[threadIdx.x] = A[(size_t)b * SP1 + threadIdx.x];
  __syncthreads();
  float acc = a_s[Ss] * hs[(size_t)b * 2048 + 1024 + col];   // s half of hs
  const float* vb = &V[(size_t)b * Ss * Hh + col];
#pragma unroll 4
  for (int t = 0; t < Ss; ++t) acc += a_s[t] * vb[(size_t)t * Hh];
  outC[(size_t)b * Hh + col] = acc;
}

// -------------------------------------------------------------------------------
extern "C" void kernel_launch(void* const* d_in, const int* in_sizes, int n_in,
                              void* d_out, int out_size, void* d_ws, size_t ws_size,
                              hipStream_t stream) {
  const float* v   = (const float*)d_in[0];
  const float* h   = (const float*)d_in[1];
  const float* Wfc = (const float*)d_in[2];
  const float* bfc = (const float*)d_in[3];
  const float* Wv  = (const float*)d_in[4];
  const float* bv  = (const float*)d_in[5];
  const float* Wh  = (const float*)d_in[6];
  const float* bh  = (const float*)d_in[7];
  const float* Ws  = (const float*)d_in[8];
  const float* bs  = (const float*)d_in[9];
  const float* Wz  = (const float*)d_in[10];
  const float* bz  = (const float*)d_in[11];
  float* out  = (float*)d_out;
  float* outA = out;                         // [256][197]
  float* outC = out + (size_t)Bb * SP1;      // [256][1024]

  float* ws  = (float*)d_ws;
  float* hs  = ws;                  // 256*2048
  float* hh  = hs + 524288;         // 256*1024
  float* sv  = hh + 262144;         // 256*1024
  float* zp  = sv + 262144;         // 4*50176
  u16*  WvT  = (u16*)(zp + 200704); // 1024*1024 bf16 (swizzled)

  k_transpose_cvt<<<256, 256, 0, stream>>>(Wv, WvT);
  k_fc<<<512, 256, 0, stream>>>(h, Wfc, bfc, hs);
  k_dual<<<512, 256, 0, stream>>>(hs, Wh, bh, Ws, bs, hh, sv);
  k_big<<<1568, 256, 0, stream>>>(v, WvT, bv, hh, Wz, zp);
  k_softmax<<<256, 256, 0, stream>>>(zp, sv, hh, Wz, bz, outA);
  k_ctx<<<1024, 256, 0, stream>>>(v, hs, outA, outC);
}